// Round 2
// baseline (1079.061 us; speedup 1.0000x reference)
//
#include <hip/hip_runtime.h>
#include <hip/hip_bf16.h>

typedef unsigned short u16;
typedef unsigned int   u32;

#define T_    120
#define D_    64
#define DFF_  128
#define DOUT_ 31
#define KPAD_ 66    // shorts per K-cache row (odd word stride 33 -> conflict-free)
#define VPAD_ 126   // shorts per V^T-cache row (odd word stride 63 -> conflict-free)

// ---------- helpers ----------
__device__ __forceinline__ float b2f(u16 u){ return __uint_as_float(((u32)u) << 16); }
__device__ __forceinline__ float2 bp2(u32 u){
  float2 r; r.x = __uint_as_float(u << 16); r.y = __uint_as_float(u & 0xffff0000u); return r;
}
// fp32 -> bf16 bits, round-to-nearest-even
__device__ __forceinline__ u16 f2bu(float f){
  u32 u = __float_as_uint(f);
  u32 r = u + 0x7fffu + ((u >> 16) & 1u);
  return (u16)(r >> 16);
}
__device__ __forceinline__ float wsum(float v){
  #pragma unroll
  for (int o = 32; o; o >>= 1) v += __shfl_xor(v, o, 64);
  return v;
}
__device__ __forceinline__ float wmax(float v){
  #pragma unroll
  for (int o = 32; o; o >>= 1) v = fmaxf(v, __shfl_xor(v, o, 64));
  return v;
}
// positional encoding value: pe[row % 10][i]
__device__ __forceinline__ float pe_val(int row, int i){
  const float coef = -0.28782313662425574f; // -ln(10000)/32
  int p = row % 10;
  float dv  = __expf((float)(i >> 1) * coef);
  float ang = (float)p * dv;
  return (i & 1) ? __cosf(ang) : __sinf(ang);
}

// ---------- kernel A: mem = audio[0] @ W_audio^T + b_audio  (120 x 64) ----------
__global__ __launch_bounds__(256) void k_mem(const float* __restrict__ audio,
                                             const float* __restrict__ Wa,
                                             const float* __restrict__ ba,
                                             float* __restrict__ mem){
  __shared__ float ash[1024];
  const int t = blockIdx.x, tid = threadIdx.x;
  for (int i = tid; i < 1024; i += 256) ash[i] = audio[t*1024 + i];
  __syncthreads();
  const int w = tid >> 6, lane = tid & 63;
  for (int d = w*16; d < w*16 + 16; ++d){
    const float4* row = (const float4*)(Wa + d*1024);
    float acc = 0.f;
    #pragma unroll
    for (int m = 0; m < 4; ++m){
      float4 wp = row[lane + 64*m];        // coalesced
      int j = 4*(lane + 64*m);
      acc += wp.x*ash[j] + wp.y*ash[j+1] + wp.z*ash[j+2] + wp.w*ash[j+3];
    }
    acc = wsum(acc);
    if (lane == 0) mem[t*64 + d] = acc + ba[d];
  }
}

// ---------- kernel B: cross[t] = (mem[t]@Wv2^T + bv2)@Wo2^T + bo2 ----------
__global__ __launch_bounds__(64) void k_cross(const float* __restrict__ mem,
                                              const float* __restrict__ Wv2, const float* __restrict__ bv2,
                                              const float* __restrict__ Wo2, const float* __restrict__ bo2,
                                              float* __restrict__ cross){
  __shared__ float msh[64], tsh[64];
  const int t = blockIdx.x, i = threadIdx.x;
  msh[i] = mem[t*64 + i];
  __syncthreads();
  const float4* r1 = (const float4*)(Wv2 + i*64);
  float a = bv2[i];
  #pragma unroll
  for (int j = 0; j < 16; ++j){ float4 w = r1[j]; a += w.x*msh[4*j] + w.y*msh[4*j+1] + w.z*msh[4*j+2] + w.w*msh[4*j+3]; }
  tsh[i] = a;
  __syncthreads();
  const float4* r2 = (const float4*)(Wo2 + i*64);
  float c = bo2[i];
  #pragma unroll
  for (int j = 0; j < 16; ++j){ float4 w = r2[j]; c += w.x*tsh[4*j] + w.y*tsh[4*j+1] + w.z*tsh[4*j+2] + w.w*tsh[4*j+3]; }
  cross[t*64 + i] = c;
}

// ---------- kernel C: the sequential 119-step scan (single block, 128 threads) ----------
__global__ __launch_bounds__(128, 1) void k_scan(
    const float* __restrict__ objW,
    const float* __restrict__ Wq, const float* __restrict__ bq,
    const float* __restrict__ Wk, const float* __restrict__ bk,
    const float* __restrict__ Wv, const float* __restrict__ bv,
    const float* __restrict__ Wo, const float* __restrict__ bo,
    const float* __restrict__ g1, const float* __restrict__ be1,
    const float* __restrict__ g2, const float* __restrict__ be2,
    const float* __restrict__ g3, const float* __restrict__ be3,
    const float* __restrict__ W1, const float* __restrict__ c1,
    const float* __restrict__ W2, const float* __restrict__ c2,
    const float* __restrict__ Wr, const float* __restrict__ br,
    const float* __restrict__ Wm, const float* __restrict__ bm,
    const float* __restrict__ cross,
    float* __restrict__ xw, float* __restrict__ Kw, float* __restrict__ Vw)
{
  // ~58 KB static LDS (under the safe 64KB/workgroup cap)
  __shared__ __align__(16) u16 Kc[T_*KPAD_];       // K cache, bf16, row-major [120][66]
  __shared__ __align__(16) u16 Vc[D_*VPAD_];       // V cache, bf16, transposed [64][126]
  __shared__ __align__(16) u16 Wq_s[D_*D_], Wk_s[D_*D_];
  __shared__ __align__(16) u16 Wm_s[D_*32];        // Wm padded 31->32 for aligned pair loads
  __shared__ float xs[D_], qs[D_], at[D_], h2s[D_], h3s[D_], fs[DFF_], sc[2*T_], rs[32];
  __shared__ float bqs[D_], bks[D_], bvs[D_], bos[D_], c2s[D_], bms[D_], cls[D_], sty[D_];
  __shared__ float c1s[DFF_], brs[32];
  __shared__ float g1s[D_], b1s[D_], g2s[D_], b2s[D_], g3s[D_], b3s[D_];

  const int tid = threadIdx.x;
  for (int i = tid; i < D_*D_; i += 128){ Wq_s[i] = f2bu(Wq[i]); Wk_s[i] = f2bu(Wk[i]); }
  for (int i = tid; i < D_*DOUT_; i += 128){ Wm_s[(i/31)*32 + (i%31)] = f2bu(Wm[i]); }
  if (tid < D_){
    bqs[tid]=bq[tid]; bks[tid]=bk[tid]; bvs[tid]=bv[tid]; bos[tid]=bo[tid];
    c2s[tid]=c2[tid]; bms[tid]=bm[tid];
    g1s[tid]=g1[tid]; b1s[tid]=be1[tid];
    g2s[tid]=g2[tid]; b2s[tid]=be2[tid];
    g3s[tid]=g3[tid]; b3s[tid]=be3[tid];
    cls[tid]=cross[119*64 + tid];                 // cross_last = cross[T-1]
    float st = objW[tid*5];                       // obj_W[:,0]
    sty[tid]=st;
    float x0 = st + pe_val(0, tid);               // x[0] = style + pe[0]
    xs[tid]=x0; xw[tid]=x0;
  }
  if (tid < DFF_)  c1s[tid]=c1[tid];
  if (tid < DOUT_) brs[tid]=br[tid];
  __syncthreads();

  for (int t = 0; t < T_-1; ++t){
    const int i = tid & 63;
    // ---- phase 1: q (wave0, LDS), k (wave1, LDS), v (wave0, global Wv) from x_t ----
    {
      const u32* wr_ = (const u32*)((tid < 64) ? (Wq_s + i*64) : (Wk_s + i*64));
      float acc = (tid < 64) ? bqs[i] : bks[i];
      #pragma unroll
      for (int j = 0; j < 32; ++j){ float2 w = bp2(wr_[j]); acc += w.x*xs[2*j] + w.y*xs[2*j+1]; }
      if (tid < 64){
        qs[i] = acc;
        const float4* vr = (const float4*)(Wv + i*64);
        float vv = bvs[i];
        #pragma unroll
        for (int j = 0; j < 16; ++j){ float4 w = vr[j]; vv += w.x*xs[4*j] + w.y*xs[4*j+1] + w.z*xs[4*j+2] + w.w*xs[4*j+3]; }
        Vc[i*VPAD_ + t] = f2bu(vv);
        Vw[t*64 + i] = vv;
      } else {
        Kc[t*KPAD_ + i] = f2bu(acc);
        Kw[t*64 + i] = acc;
      }
    }
    __syncthreads();
    // ---- phase 2: scores for j <= t ----
    if (tid <= t){
      const u32* kr = (const u32*)(Kc + tid*KPAD_);
      float s0 = 0.f, s1 = 0.f;
      #pragma unroll
      for (int j = 0; j < 16; ++j){ float2 w = bp2(kr[j]); s0 += w.x*qs[2*j] + w.y*qs[2*j+1]; }
      #pragma unroll
      for (int j = 16; j < 32; ++j){ float2 w = bp2(kr[j]); s1 += w.x*qs[2*j] + w.y*qs[2*j+1]; }
      int rel = (t - tid) / 10;
      sc[tid]      = s0*0.17677669529663687f - 0.0625f*(float)rel;
      sc[T_ + tid] = s1*0.17677669529663687f - 0.00390625f*(float)rel;
    }
    __syncthreads();
    // ---- phase 3: softmax (wave0 = head0, wave1 = head1) ----
    {
      const int h = tid >> 6, lane = tid & 63;
      float v0 = (lane      <= t) ? sc[h*T_ + lane]      : -1e30f;
      float v1 = (lane + 64 <= t) ? sc[h*T_ + lane + 64] : -1e30f;
      float m  = wmax(fmaxf(v0, v1));
      float e0 = (lane      <= t) ? __expf(v0 - m) : 0.f;
      float e1 = (lane + 64 <= t) ? __expf(v1 - m) : 0.f;
      float s  = wsum(e0 + e1);
      float inv = 1.f / s;
      if (lane      <= t) sc[h*T_ + lane]      = e0*inv;
      if (lane + 64 <= t) sc[h*T_ + lane + 64] = e1*inv;
    }
    __syncthreads();
    // ---- phase 4: attn out (lane d reads V^T row d) ----
    if (tid < 64){
      const int h = tid >> 5;
      const float* a = sc + h*T_;
      const u16* vrow = Vc + tid*VPAD_;
      float acc = 0.f;
      int j = 0;
      for (; j + 1 <= t; j += 2){
        float2 w = bp2(*(const u32*)(vrow + j));
        acc += w.x*a[j] + w.y*a[j+1];
      }
      if (j <= t) acc += b2f(vrow[j]) * a[j];
      at[tid] = acc;
    }
    __syncthreads();
    // ---- phase 5: sa = attn@Wo^T + bo ; h1 = LN1(x+sa) ; h2 = LN2(h1+cross_last) ----
    if (tid < 64){
      const float4* orow = (const float4*)(Wo + tid*64);
      float acc = bos[tid];
      #pragma unroll
      for (int j = 0; j < 16; ++j){ float4 w = orow[j]; acc += w.x*at[4*j] + w.y*at[4*j+1] + w.z*at[4*j+2] + w.w*at[4*j+3]; }
      float y = xs[tid] + acc;
      float s = wsum(y), s2 = wsum(y*y);
      float m = s*(1.f/64.f), var = s2*(1.f/64.f) - m*m;
      float r = rsqrtf(var + 1e-5f);
      float h1 = (y - m)*r*g1s[tid] + b1s[tid];
      float z = h1 + cls[tid];
      float sz = wsum(z), sz2 = wsum(z*z);
      float mz = sz*(1.f/64.f), vz = sz2*(1.f/64.f) - mz*mz;
      float rz = rsqrtf(vz + 1e-5f);
      h2s[tid] = (z - mz)*rz*g2s[tid] + b2s[tid];
    }
    __syncthreads();
    // ---- phase 6: FFN1 (all 128 threads) ----
    {
      const float4* w1r = (const float4*)(W1 + tid*64);
      float acc = c1s[tid];
      #pragma unroll
      for (int j = 0; j < 16; ++j){ float4 w = w1r[j]; acc += w.x*h2s[4*j] + w.y*h2s[4*j+1] + w.z*h2s[4*j+2] + w.w*h2s[4*j+3]; }
      fs[tid] = fmaxf(acc, 0.f);
    }
    __syncthreads();
    // ---- phase 7: FFN2 + LN3 ----
    if (tid < 64){
      const float4* w2r = (const float4*)(W2 + tid*128);
      float acc = c2s[tid];
      #pragma unroll
      for (int j = 0; j < 32; ++j){ float4 w = w2r[j]; acc += w.x*fs[4*j] + w.y*fs[4*j+1] + w.z*fs[4*j+2] + w.w*fs[4*j+3]; }
      float y = h2s[tid] + acc;
      float s = wsum(y), s2 = wsum(y*y);
      float m = s*(1.f/64.f), var = s2*(1.f/64.f) - m*m;
      float r = rsqrtf(var + 1e-5f);
      h3s[tid] = (y - m)*r*g3s[tid] + b3s[tid];
    }
    __syncthreads();
    // ---- phase 8: r = h3@Wr^T + br ----
    if (tid < DOUT_){
      const float4* rr = (const float4*)(Wr + tid*64);
      float acc = brs[tid];
      #pragma unroll
      for (int j = 0; j < 16; ++j){ float4 w = rr[j]; acc += w.x*h3s[4*j] + w.y*h3s[4*j+1] + w.z*h3s[4*j+2] + w.w*h3s[4*j+3]; }
      rs[tid] = acc;
    }
    __syncthreads();
    // ---- phase 9: new = r@Wm^T + bm + style ; x_{t+1} = new + pe ----
    if (tid < 64){
      const u16* mrow = Wm_s + tid*32;
      float acc = bms[tid] + sty[tid];
      #pragma unroll
      for (int j = 0; j < 15; ++j){ float2 w = bp2(*(const u32*)(mrow + 2*j)); acc += w.x*rs[2*j] + w.y*rs[2*j+1]; }
      acc += b2f(mrow[30]) * rs[30];
      float xn = acc + pe_val(t + 1, tid);
      xs[tid] = xn;
      xw[(t+1)*64 + tid] = xn;
    }
    __syncthreads();
  }
  // ---- epilogue: k,v for row 119 (needed by the final pass) ----
  {
    const int i = tid & 63;
    if (tid < 64){
      const u32* wr_ = (const u32*)(Wk_s + i*64);
      float acc = bks[i];
      #pragma unroll
      for (int j = 0; j < 32; ++j){ float2 w = bp2(wr_[j]); acc += w.x*xs[2*j] + w.y*xs[2*j+1]; }
      Kw[119*64 + i] = acc;
    } else {
      const float4* vr = (const float4*)(Wv + i*64);
      float acc = bvs[i];
      #pragma unroll
      for (int j = 0; j < 16; ++j){ float4 w = vr[j]; acc += w.x*xs[4*j] + w.y*xs[4*j+1] + w.z*xs[4*j+2] + w.w*xs[4*j+3]; }
      Vw[119*64 + i] = acc;
    }
  }
}

// ---------- kernel D: final full pass, one block per row ----------
__global__ __launch_bounds__(128) void k_final(
    const float* __restrict__ Wq, const float* __restrict__ bq,
    const float* __restrict__ Wo, const float* __restrict__ bo,
    const float* __restrict__ g1, const float* __restrict__ be1,
    const float* __restrict__ g2, const float* __restrict__ be2,
    const float* __restrict__ g3, const float* __restrict__ be3,
    const float* __restrict__ W1, const float* __restrict__ c1,
    const float* __restrict__ W2, const float* __restrict__ c2,
    const float* __restrict__ Wr, const float* __restrict__ br,
    const float* __restrict__ cross, const float* __restrict__ xw,
    const float* __restrict__ Kw, const float* __restrict__ Vw,
    float* __restrict__ out)
{
  __shared__ float xs[64], qs[64], at[64], h2s[64], h3s[64], fs[128], sc[2*T_];
  const int irow = blockIdx.x, tid = threadIdx.x;
  if (tid < 64) xs[tid] = xw[irow*64 + tid];
  __syncthreads();
  if (tid < 64){
    const float4* wr_ = (const float4*)(Wq + tid*64);
    float acc = bq[tid];
    #pragma unroll
    for (int j = 0; j < 16; ++j){ float4 w = wr_[j]; acc += w.x*xs[4*j] + w.y*xs[4*j+1] + w.z*xs[4*j+2] + w.w*xs[4*j+3]; }
    qs[tid] = acc;
  }
  __syncthreads();
  if (tid <= irow){
    const float* kr = Kw + tid*64;
    float s0 = 0.f, s1 = 0.f;
    #pragma unroll
    for (int d = 0; d < 32; ++d) s0 += qs[d]      * kr[d];
    #pragma unroll
    for (int d = 0; d < 32; ++d) s1 += qs[32 + d] * kr[32 + d];
    int rel = (irow - tid) / 10;
    sc[tid]      = s0*0.17677669529663687f - 0.0625f*(float)rel;
    sc[T_ + tid] = s1*0.17677669529663687f - 0.00390625f*(float)rel;
  }
  __syncthreads();
  {
    const int h = tid >> 6, lane = tid & 63;
    float v0 = (lane      <= irow) ? sc[h*T_ + lane]      : -1e30f;
    float v1 = (lane + 64 <= irow) ? sc[h*T_ + lane + 64] : -1e30f;
    float m  = wmax(fmaxf(v0, v1));
    float e0 = (lane      <= irow) ? __expf(v0 - m) : 0.f;
    float e1 = (lane + 64 <= irow) ? __expf(v1 - m) : 0.f;
    float s  = wsum(e0 + e1);
    float inv = 1.f / s;
    if (lane      <= irow) sc[h*T_ + lane]      = e0*inv;
    if (lane + 64 <= irow) sc[h*T_ + lane + 64] = e1*inv;
  }
  __syncthreads();
  if (tid < 64){
    const int h = tid >> 5;
    const float* a = sc + h*T_;
    float acc = 0.f;
    for (int j = 0; j <= irow; ++j) acc += a[j] * Vw[j*64 + tid];  // coalesced
    at[tid] = acc;
  }
  __syncthreads();
  if (tid < 64){
    const float4* orow = (const float4*)(Wo + tid*64);
    float acc = bo[tid];
    #pragma unroll
    for (int j = 0; j < 16; ++j){ float4 w = orow[j]; acc += w.x*at[4*j] + w.y*at[4*j+1] + w.z*at[4*j+2] + w.w*at[4*j+3]; }
    float y = xs[tid] + acc;
    float s = wsum(y), s2 = wsum(y*y);
    float m = s*(1.f/64.f), var = s2*(1.f/64.f) - m*m;
    float r = rsqrtf(var + 1e-5f);
    float h1 = (y - m)*r*g1[tid] + be1[tid];
    float z = h1 + cross[irow*64 + tid];
    float sz = wsum(z), sz2 = wsum(z*z);
    float mz = sz*(1.f/64.f), vz = sz2*(1.f/64.f) - mz*mz;
    float rz = rsqrtf(vz + 1e-5f);
    h2s[tid] = (z - mz)*rz*g2[tid] + be2[tid];
  }
  __syncthreads();
  {
    const float4* w1r = (const float4*)(W1 + tid*64);
    float acc = c1[tid];
    #pragma unroll
    for (int j = 0; j < 16; ++j){ float4 w = w1r[j]; acc += w.x*h2s[4*j] + w.y*h2s[4*j+1] + w.z*h2s[4*j+2] + w.w*h2s[4*j+3]; }
    fs[tid] = fmaxf(acc, 0.f);
  }
  __syncthreads();
  if (tid < 64){
    const float4* w2r = (const float4*)(W2 + tid*128);
    float acc = c2[tid];
    #pragma unroll
    for (int j = 0; j < 32; ++j){ float4 w = w2r[j]; acc += w.x*fs[4*j] + w.y*fs[4*j+1] + w.z*fs[4*j+2] + w.w*fs[4*j+3]; }
    float y = h2s[tid] + acc;
    float s = wsum(y), s2 = wsum(y*y);
    float m = s*(1.f/64.f), var = s2*(1.f/64.f) - m*m;
    float r = rsqrtf(var + 1e-5f);
    h3s[tid] = (y - m)*r*g3[tid] + be3[tid];
  }
  __syncthreads();
  if (tid < DOUT_){
    const float4* rr = (const float4*)(Wr + tid*64);
    float acc = br[tid];
    #pragma unroll
    for (int j = 0; j < 16; ++j){ float4 w = rr[j]; acc += w.x*h3s[4*j] + w.y*h3s[4*j+1] + w.z*h3s[4*j+2] + w.w*h3s[4*j+3]; }
    out[irow*DOUT_ + tid] = acc;
  }
}

extern "C" void kernel_launch(void* const* d_in, const int* in_sizes, int n_in,
                              void* d_out, int out_size, void* d_ws, size_t ws_size,
                              hipStream_t stream){
  const float* audio=(const float*)d_in[0];
  const float* Wa   =(const float*)d_in[1];
  const float* ba   =(const float*)d_in[2];
  const float* objW =(const float*)d_in[3];
  const float* Wq   =(const float*)d_in[4];
  const float* bq   =(const float*)d_in[5];
  const float* Wk   =(const float*)d_in[6];
  const float* bk   =(const float*)d_in[7];
  const float* Wv   =(const float*)d_in[8];
  const float* bv   =(const float*)d_in[9];
  const float* Wo   =(const float*)d_in[10];
  const float* bo   =(const float*)d_in[11];
  const float* Wv2  =(const float*)d_in[12];
  const float* bv2  =(const float*)d_in[13];
  const float* Wo2  =(const float*)d_in[14];
  const float* bo2  =(const float*)d_in[15];
  const float* g1   =(const float*)d_in[16];
  const float* be1  =(const float*)d_in[17];
  const float* g2   =(const float*)d_in[18];
  const float* be2  =(const float*)d_in[19];
  const float* g3   =(const float*)d_in[20];
  const float* be3  =(const float*)d_in[21];
  const float* W1   =(const float*)d_in[22];
  const float* c1   =(const float*)d_in[23];
  const float* W2   =(const float*)d_in[24];
  const float* c2   =(const float*)d_in[25];
  const float* Wr   =(const float*)d_in[26];
  const float* br   =(const float*)d_in[27];
  const float* Wm   =(const float*)d_in[28];
  const float* bm   =(const float*)d_in[29];

  float* ws    = (float*)d_ws;
  float* mem   = ws;           // 120*64
  float* cross = ws + 7680;    // 120*64
  float* xw    = ws + 15360;   // 120*64  (x = emb + pe)
  float* Kw    = ws + 23040;   // 120*64
  float* Vw    = ws + 30720;   // 120*64
  float* out = (float*)d_out;

  k_mem  <<<dim3(120), dim3(256), 0, stream>>>(audio, Wa, ba, mem);
  k_cross<<<dim3(120), dim3(64),  0, stream>>>(mem, Wv2, bv2, Wo2, bo2, cross);
  k_scan <<<dim3(1),   dim3(128), 0, stream>>>(objW, Wq, bq, Wk, bk, Wv, bv, Wo, bo,
                                               g1, be1, g2, be2, g3, be3,
                                               W1, c1, W2, c2, Wr, br, Wm, bm,
                                               cross, xw, Kw, Vw);
  k_final<<<dim3(120), dim3(128), 0, stream>>>(Wq, bq, Wo, bo, g1, be1, g2, be2, g3, be3,
                                               W1, c1, W2, c2, Wr, br,
                                               cross, xw, Kw, Vw, out);
}

// Round 3
// 881.488 us; speedup vs baseline: 1.2241x; 1.2241x over previous
//
#include <hip/hip_runtime.h>

typedef unsigned short u16;
typedef unsigned int   u32;

#define T_    120
#define D_    64
#define DFF_  128
#define DOUT_ 31
#define KPAD_ 66    // shorts per K-cache row (33 words, odd -> conflict-free)
#define VPAD_ 126   // shorts per V^T-cache row (63 words, odd -> conflict-free)

// ---------- helpers ----------
__device__ __forceinline__ float b2f(u16 u){ return __uint_as_float(((u32)u) << 16); }
__device__ __forceinline__ float2 bp2(u32 u){
  float2 r; r.x = __uint_as_float(u << 16); r.y = __uint_as_float(u & 0xffff0000u); return r;
}
__device__ __forceinline__ u16 f2bu(float f){
  u32 u = __float_as_uint(f);
  u32 r = u + 0x7fffu + ((u >> 16) & 1u);
  return (u16)(r >> 16);
}
// compiler fence + wave scheduling barrier: wave-synchronous LDS handoff (DS pipe is in-order per wave)
#define WSYNC() do{ __asm__ __volatile__("" ::: "memory"); __builtin_amdgcn_wave_barrier(); }while(0)

// wave64 sum via DPP (row_shr scan + bcast15/31). Invalid lanes contribute 0
// regardless of bound_ctrl interpretation (old=0 AND bound_ctrl=true).
__device__ __forceinline__ float dpp_sum(float x){
  int t;
  t = __builtin_amdgcn_update_dpp(0, __float_as_int(x), 0x111, 0xf, 0xf, true); x += __int_as_float(t);
  t = __builtin_amdgcn_update_dpp(0, __float_as_int(x), 0x112, 0xf, 0xf, true); x += __int_as_float(t);
  t = __builtin_amdgcn_update_dpp(0, __float_as_int(x), 0x114, 0xf, 0xf, true); x += __int_as_float(t);
  t = __builtin_amdgcn_update_dpp(0, __float_as_int(x), 0x118, 0xf, 0xf, true); x += __int_as_float(t);
  t = __builtin_amdgcn_update_dpp(0, __float_as_int(x), 0x142, 0xf, 0xf, true); x += __int_as_float(t);
  t = __builtin_amdgcn_update_dpp(0, __float_as_int(x), 0x143, 0xf, 0xf, true); x += __int_as_float(t);
  return __int_as_float(__builtin_amdgcn_readlane(__float_as_int(x), 63));
}
// wave64 max via DPP; REQUIRES true max > 0 (callers shift by +16384)
__device__ __forceinline__ float dpp_max_pos(float x){
  int t;
  t = __builtin_amdgcn_update_dpp(0, __float_as_int(x), 0x111, 0xf, 0xf, true); x = fmaxf(x, __int_as_float(t));
  t = __builtin_amdgcn_update_dpp(0, __float_as_int(x), 0x112, 0xf, 0xf, true); x = fmaxf(x, __int_as_float(t));
  t = __builtin_amdgcn_update_dpp(0, __float_as_int(x), 0x114, 0xf, 0xf, true); x = fmaxf(x, __int_as_float(t));
  t = __builtin_amdgcn_update_dpp(0, __float_as_int(x), 0x118, 0xf, 0xf, true); x = fmaxf(x, __int_as_float(t));
  t = __builtin_amdgcn_update_dpp(0, __float_as_int(x), 0x142, 0xf, 0xf, true); x = fmaxf(x, __int_as_float(t));
  t = __builtin_amdgcn_update_dpp(0, __float_as_int(x), 0x143, 0xf, 0xf, true); x = fmaxf(x, __int_as_float(t));
  return __int_as_float(__builtin_amdgcn_readlane(__float_as_int(x), 63));
}
__device__ __forceinline__ float pe_val(int row, int i){
  const float coef = -0.28782313662425574f; // -ln(10000)/32
  int p = row % 10;
  float dv  = __expf((float)(i >> 1) * coef);
  float ang = (float)p * dv;
  return (i & 1) ? __cosf(ang) : __sinf(ang);
}

// ---------- kernel P: fp32 -> bf16 weight conversion into workspace ----------
__global__ __launch_bounds__(256) void k_prep(const float* __restrict__ Wv, const float* __restrict__ Wo,
                                              const float* __restrict__ W1, const float* __restrict__ W2,
                                              const float* __restrict__ Wr,
                                              u16* __restrict__ wvb, u16* __restrict__ wob,
                                              u16* __restrict__ w1b, u16* __restrict__ w2b,
                                              u16* __restrict__ wrb){
  int i0 = blockIdx.x*256 + threadIdx.x, stride = gridDim.x*256;
  for (int i = i0; i < 4096; i += stride){ wvb[i] = f2bu(Wv[i]); wob[i] = f2bu(Wo[i]); }
  for (int i = i0; i < 8192; i += stride){ w1b[i] = f2bu(W1[i]); w2b[i] = f2bu(W2[i]); }
  for (int i = i0; i < 1984; i += stride){ wrb[i] = f2bu(Wr[i]); }
}

// ---------- kernel A: mem = audio[0] @ W_audio^T + b_audio  (120 x 64) ----------
__global__ __launch_bounds__(256) void k_mem(const float* __restrict__ audio,
                                             const float* __restrict__ Wa,
                                             const float* __restrict__ ba,
                                             float* __restrict__ mem){
  __shared__ float ash[1024];
  const int t = blockIdx.x, tid = threadIdx.x;
  for (int i = tid; i < 1024; i += 256) ash[i] = audio[t*1024 + i];
  __syncthreads();
  const int w = tid >> 6, lane = tid & 63;
  for (int d = w*16; d < w*16 + 16; ++d){
    const float4* row = (const float4*)(Wa + d*1024);
    float acc = 0.f;
    #pragma unroll
    for (int m = 0; m < 4; ++m){
      float4 wp = row[lane + 64*m];
      int j = 4*(lane + 64*m);
      acc += wp.x*ash[j] + wp.y*ash[j+1] + wp.z*ash[j+2] + wp.w*ash[j+3];
    }
    acc = dpp_sum(acc);
    if (lane == 0) mem[t*64 + d] = acc + ba[d];
  }
}

// ---------- kernel B: cross[t] = (mem[t]@Wv2^T + bv2)@Wo2^T + bo2 ----------
__global__ __launch_bounds__(64) void k_cross(const float* __restrict__ mem,
                                              const float* __restrict__ Wv2, const float* __restrict__ bv2,
                                              const float* __restrict__ Wo2, const float* __restrict__ bo2,
                                              float* __restrict__ cross){
  __shared__ float msh[64], tsh[64];
  const int t = blockIdx.x, i = threadIdx.x;
  msh[i] = mem[t*64 + i];
  __syncthreads();
  const float4* r1 = (const float4*)(Wv2 + i*64);
  float a = bv2[i];
  #pragma unroll
  for (int j = 0; j < 16; ++j){ float4 w = r1[j]; a += w.x*msh[4*j] + w.y*msh[4*j+1] + w.z*msh[4*j+2] + w.w*msh[4*j+3]; }
  tsh[i] = a;
  __syncthreads();
  const float4* r2 = (const float4*)(Wo2 + i*64);
  float c = bo2[i];
  #pragma unroll
  for (int j = 0; j < 16; ++j){ float4 w = r2[j]; c += w.x*tsh[4*j] + w.y*tsh[4*j+1] + w.z*tsh[4*j+2] + w.w*tsh[4*j+3]; }
  cross[t*64 + i] = c;
}

// ---------- kernel C: the sequential 119-step scan (single block, 128 threads) ----------
__global__ __launch_bounds__(128, 1) void k_scan(
    const float* __restrict__ objW,
    const float* __restrict__ Wq, const float* __restrict__ bq,
    const float* __restrict__ Wk, const float* __restrict__ bk,
    const float* __restrict__ bv, const float* __restrict__ bo,
    const float* __restrict__ g1, const float* __restrict__ be1,
    const float* __restrict__ g2, const float* __restrict__ be2,
    const float* __restrict__ g3, const float* __restrict__ be3,
    const float* __restrict__ c1, const float* __restrict__ c2,
    const float* __restrict__ br, const float* __restrict__ Wm, const float* __restrict__ bm,
    const float* __restrict__ cross,
    const u16* __restrict__ wv_b, const u16* __restrict__ wo_b,
    const u16* __restrict__ w1_b, const u16* __restrict__ w2_b, const u16* __restrict__ wr_b,
    float* __restrict__ xw, float* __restrict__ Kw, float* __restrict__ Vw)
{
  // ~60.4 KB static LDS
  __shared__ u32 Wqk[128][32];                 // rows 0-63: Wq; 64-127: Wk; word w at [r][w^(r&31)]
  __shared__ u32 Wms[64][16];                  // Wm padded 31->32, word w at [r][w^(r&15)]
  __shared__ __align__(16) u16 Kc[128*KPAD_];  // K cache bf16 (128 rows so j+64 reads stay in-bounds)
  __shared__ __align__(16) u16 Vc[D_*VPAD_];   // V^T cache bf16
  __shared__ float xs[64], qs[64], at[64], h2s[64], h3s[64], fs[128], sc[256], rs[32];
  __shared__ float bqs[64], bks[64], bvs[64], bos[64], c2s[64], bmsty[64], cls[64];
  __shared__ float c1s[128], brs[32];
  __shared__ float g1s[64], b1s[64], g2s[64], b2s[64], g3s[64], b3s[64];

  const int tid = threadIdx.x;
  // stage swizzled bf16 weights
  for (int idx = tid; idx < 128*32; idx += 128){
    int r = idx >> 5, w = idx & 31;
    const float* src = (r < 64) ? (Wq + r*64) : (Wk + (r-64)*64);
    Wqk[r][w ^ (r & 31)] = (u32)f2bu(src[2*w]) | ((u32)f2bu(src[2*w+1]) << 16);
  }
  for (int idx = tid; idx < 64*16; idx += 128){
    int r = idx >> 4, w = idx & 15;
    float lo = Wm[r*31 + 2*w];
    float hi = (2*w+1 < 31) ? Wm[r*31 + 2*w + 1] : 0.f;
    Wms[r][w ^ (r & 15)] = (u32)f2bu(lo) | ((u32)f2bu(hi) << 16);
  }
  for (int i = tid; i < D_*VPAD_/2; i += 128) ((u32*)Vc)[i] = 0;  // avoid NaN-garbage * 0
  if (tid < 64){
    bqs[tid]=bq[tid]; bks[tid]=bk[tid]; bvs[tid]=bv[tid]; bos[tid]=bo[tid];
    c2s[tid]=c2[tid];
    float st = objW[tid*5];                     // obj_W[:,0]
    bmsty[tid]=bm[tid]+st;
    cls[tid]=cross[119*64 + tid];               // cross_last
    g1s[tid]=g1[tid]; b1s[tid]=be1[tid];
    g2s[tid]=g2[tid]; b2s[tid]=be2[tid];
    g3s[tid]=g3[tid]; b3s[tid]=be3[tid];
    float x0 = st + pe_val(0, tid);
    xs[tid]=x0; xw[tid]=x0;
  }
  c1s[tid] = c1[tid];
  if (tid < 32){ brs[tid] = (tid < 31) ? br[tid] : 0.f; rs[tid] = 0.f; }
  __syncthreads();

  for (int t = 0; t < T_-1; ++t){
    const int i = tid & 63;
    // ---- P1: q (wave0, LDS) + v (wave0, global bf16) ; k (wave1, LDS) ----
    {
      const u32* wr_ = Wqk[tid];
      const int sw = tid & 31;
      float acc = (tid < 64) ? bqs[i] : bks[i];
      #pragma unroll
      for (int w = 0; w < 32; ++w){ float2 p = bp2(wr_[w ^ sw]); acc += p.x*xs[2*w] + p.y*xs[2*w+1]; }
      if (tid < 64){
        qs[i] = acc;
        const u32* vr = (const u32*)(wv_b + i*64);
        float vv = bvs[i];
        #pragma unroll
        for (int w = 0; w < 32; ++w){ float2 p = bp2(vr[w]); vv += p.x*xs[2*w] + p.y*xs[2*w+1]; }
        Vc[i*VPAD_ + t] = f2bu(vv);
        Vw[t*64 + i] = vv;
      } else {
        Kc[t*KPAD_ + i] = f2bu(acc);
        Kw[t*64 + i] = acc;
      }
    }
    __syncthreads();
    // ---- P2+P3 fused: wave h computes head h scores (reg) + softmax (DPP), writes zero-padded sc ----
    {
      const int h = tid >> 6, j = tid & 63;
      const float* qh = qs + h*32;
      const u32* kr0 = (const u32*)(Kc + j*KPAD_) + h*16;
      const u32* kr1 = (const u32*)(Kc + (j+64)*KPAD_) + h*16;
      float d0 = 0.f, d1 = 0.f;
      #pragma unroll
      for (int w = 0; w < 16; ++w){
        float2 p0 = bp2(kr0[w]); float2 p1 = bp2(kr1[w]);
        float xa = qh[2*w], xb = qh[2*w+1];
        d0 += p0.x*xa + p0.y*xb; d1 += p1.x*xa + p1.y*xb;
      }
      const float slope = h ? 0.00390625f : 0.0625f;
      float s0 = (j      <= t) ? d0*0.17677669529663687f - slope*(float)((t-j)/10)    : -1e30f;
      float s1 = (j + 64 <= t) ? d1*0.17677669529663687f - slope*(float)((t-j-64)/10) : -1e30f;
      float m = dpp_max_pos(fmaxf(s0, s1) + 16384.f) - 16384.f;
      float e0 = (j      <= t) ? __expf(s0 - m) : 0.f;
      float e1 = (j + 64 <= t) ? __expf(s1 - m) : 0.f;
      float inv = 1.f / dpp_sum(e0 + e1);
      sc[h*128 + j]      = e0*inv;
      sc[h*128 + j + 64] = e1*inv;
    }
    __syncthreads();
    // ---- P4: attn out, fixed 120-trip fully unrolled, 4 accumulators ----
    if (tid < 64){
      const float* a = sc + (tid >> 5)*128;
      const u16* vrow = Vc + tid*VPAD_;
      float a0=0.f,a1=0.f,a2=0.f,a3=0.f;
      #pragma unroll
      for (int w = 0; w < 15; ++w){
        float2 p0 = bp2(*(const u32*)(vrow + 8*w));
        float2 p1 = bp2(*(const u32*)(vrow + 8*w + 2));
        float2 p2 = bp2(*(const u32*)(vrow + 8*w + 4));
        float2 p3 = bp2(*(const u32*)(vrow + 8*w + 6));
        a0 += p0.x*a[8*w]   + p0.y*a[8*w+1];
        a1 += p1.x*a[8*w+2] + p1.y*a[8*w+3];
        a2 += p2.x*a[8*w+4] + p2.y*a[8*w+5];
        a3 += p3.x*a[8*w+6] + p3.y*a[8*w+7];
      }
      at[tid] = (a0+a1)+(a2+a3);
    }
    WSYNC();
    // ---- P5: sa = at@Wo^T + bo ; LN1 ; +cross_last ; LN2  (wave0, wave-sync) ----
    if (tid < 64){
      const u32* orow = (const u32*)(wo_b + tid*64);
      float acc = bos[tid];
      #pragma unroll
      for (int w = 0; w < 32; ++w){ float2 p = bp2(orow[w]); acc += p.x*at[2*w] + p.y*at[2*w+1]; }
      float y = xs[tid] + acc;
      float s = dpp_sum(y), s2 = dpp_sum(y*y);
      float m = s*(1.f/64.f), var = fmaxf(s2*(1.f/64.f) - m*m, 0.f);
      float h1 = (y - m)*rsqrtf(var + 1e-5f)*g1s[tid] + b1s[tid];
      float z = h1 + cls[tid];
      float sz = dpp_sum(z), sz2 = dpp_sum(z*z);
      float mz = sz*(1.f/64.f), vz = fmaxf(sz2*(1.f/64.f) - mz*mz, 0.f);
      h2s[tid] = (z - mz)*rsqrtf(vz + 1e-5f)*g2s[tid] + b2s[tid];
    }
    __syncthreads();
    // ---- P6: FFN1 (128 threads) ----
    {
      const u32* w1r = (const u32*)(w1_b + tid*64);
      float acc = c1s[tid];
      #pragma unroll
      for (int w = 0; w < 32; ++w){ float2 p = bp2(w1r[w]); acc += p.x*h2s[2*w] + p.y*h2s[2*w+1]; }
      fs[tid] = fmaxf(acc, 0.f);
    }
    __syncthreads();
    // ---- P7: FFN2 + LN3 (wave0) ----
    if (tid < 64){
      const u32* w2r = (const u32*)(w2_b + tid*128);
      float acc = c2s[tid];
      #pragma unroll
      for (int w = 0; w < 64; ++w){ float2 p = bp2(w2r[w]); acc += p.x*fs[2*w] + p.y*fs[2*w+1]; }
      float y = h2s[tid] + acc;
      float s = dpp_sum(y), s2 = dpp_sum(y*y);
      float m = s*(1.f/64.f), var = fmaxf(s2*(1.f/64.f) - m*m, 0.f);
      h3s[tid] = (y - m)*rsqrtf(var + 1e-5f)*g3s[tid] + b3s[tid];
    }
    WSYNC();
    // ---- P8: r = h3@Wr^T + br (lanes 0..30, wave-sync) ----
    if (tid < DOUT_){
      const u32* rr = (const u32*)(wr_b + tid*64);
      float acc = brs[tid];
      #pragma unroll
      for (int w = 0; w < 32; ++w){ float2 p = bp2(rr[w]); acc += p.x*h3s[2*w] + p.y*h3s[2*w+1]; }
      rs[tid] = acc;
    }
    WSYNC();
    // ---- P9: new = r@Wm^T + bm + style ; x_{t+1} = new + pe (wave0, wave-sync) ----
    if (tid < 64){
      const u32* mrow = Wms[tid];
      const int sw = tid & 15;
      float acc = bmsty[tid];
      #pragma unroll
      for (int w = 0; w < 16; ++w){ float2 p = bp2(mrow[w ^ sw]); acc += p.x*rs[2*w] + p.y*rs[2*w+1]; }
      float xn = acc + pe_val(t + 1, tid);
      xs[tid] = xn;
      xw[(t+1)*64 + tid] = xn;
    }
    __syncthreads();
  }
  // ---- epilogue: k,v for row 119 ----
  {
    const int i = tid & 63;
    if (tid < 64){
      const u32* wr_ = Wqk[64 + i];
      const int sw = i & 31;
      float acc = bks[i];
      #pragma unroll
      for (int w = 0; w < 32; ++w){ float2 p = bp2(wr_[w ^ sw]); acc += p.x*xs[2*w] + p.y*xs[2*w+1]; }
      Kw[119*64 + i] = acc;
    } else {
      const u32* vr = (const u32*)(wv_b + i*64);
      float acc = bvs[i];
      #pragma unroll
      for (int w = 0; w < 32; ++w){ float2 p = bp2(vr[w]); acc += p.x*xs[2*w] + p.y*xs[2*w+1]; }
      Vw[119*64 + i] = acc;
    }
  }
}

// ---------- kernel D: final full pass, one block per row ----------
__global__ __launch_bounds__(128) void k_final(
    const float* __restrict__ Wq, const float* __restrict__ bq, const float* __restrict__ bo,
    const float* __restrict__ g1, const float* __restrict__ be1,
    const float* __restrict__ g2, const float* __restrict__ be2,
    const float* __restrict__ g3, const float* __restrict__ be3,
    const float* __restrict__ c1, const float* __restrict__ c2, const float* __restrict__ br,
    const u16* __restrict__ wo_b, const u16* __restrict__ w1_b,
    const u16* __restrict__ w2_b, const u16* __restrict__ wr_b,
    const float* __restrict__ cross, const float* __restrict__ xw,
    const float* __restrict__ Kw, const float* __restrict__ Vw,
    float* __restrict__ out)
{
  __shared__ float xs[64], qs[64], at[64], h2s[64], h3s[64], fs[128], sc[256];
  const int irow = blockIdx.x, tid = threadIdx.x;
  if (tid < 64) xs[tid] = xw[irow*64 + tid];
  __syncthreads();
  if (tid < 64){
    const float4* wr_ = (const float4*)(Wq + tid*64);
    float acc = bq[tid];
    #pragma unroll
    for (int j = 0; j < 16; ++j){ float4 w = wr_[j]; acc += w.x*xs[4*j] + w.y*xs[4*j+1] + w.z*xs[4*j+2] + w.w*xs[4*j+3]; }
    qs[tid] = acc;
  }
  __syncthreads();
  // fused scores + softmax (wave h = head h; positions j, j+64)
  {
    const int h = tid >> 6, j = tid & 63;
    const float* qh = qs + h*32;
    float d0 = 0.f, d1 = 0.f;
    const float4* k0 = (const float4*)(Kw + j*64 + h*32);
    #pragma unroll
    for (int w = 0; w < 8; ++w){ float4 p = k0[w]; d0 += p.x*qh[4*w] + p.y*qh[4*w+1] + p.z*qh[4*w+2] + p.w*qh[4*w+3]; }
    if (j < 56){
      const float4* k1 = (const float4*)(Kw + (j+64)*64 + h*32);
      #pragma unroll
      for (int w = 0; w < 8; ++w){ float4 p = k1[w]; d1 += p.x*qh[4*w] + p.y*qh[4*w+1] + p.z*qh[4*w+2] + p.w*qh[4*w+3]; }
    }
    const float slope = h ? 0.00390625f : 0.0625f;
    float s0 = (j      <= irow) ? d0*0.17677669529663687f - slope*(float)((irow-j)/10)    : -1e30f;
    float s1 = (j + 64 <= irow) ? d1*0.17677669529663687f - slope*(float)((irow-j-64)/10) : -1e30f;
    float m = dpp_max_pos(fmaxf(s0, s1) + 16384.f) - 16384.f;
    float e0 = (j      <= irow) ? __expf(s0 - m) : 0.f;
    float e1 = (j + 64 <= irow) ? __expf(s1 - m) : 0.f;
    float inv = 1.f / dpp_sum(e0 + e1);
    sc[h*128 + j]      = e0*inv;
    sc[h*128 + j + 64] = e1*inv;
  }
  __syncthreads();
  if (tid < 64){
    const float* a = sc + (tid >> 5)*128;
    float a0=0.f,a1=0.f,a2=0.f,a3=0.f;
    #pragma unroll
    for (int jj = 0; jj < 30; ++jj){
      a0 += a[4*jj]   * Vw[(4*jj)*64   + tid];
      a1 += a[4*jj+1] * Vw[(4*jj+1)*64 + tid];
      a2 += a[4*jj+2] * Vw[(4*jj+2)*64 + tid];
      a3 += a[4*jj+3] * Vw[(4*jj+3)*64 + tid];
    }
    at[tid] = (a0+a1)+(a2+a3);
  }
  __syncthreads();
  if (tid < 64){
    const u32* orow = (const u32*)(wo_b + tid*64);
    float acc = bo[tid];
    #pragma unroll
    for (int w = 0; w < 32; ++w){ float2 p = bp2(orow[w]); acc += p.x*at[2*w] + p.y*at[2*w+1]; }
    float y = xs[tid] + acc;
    float s = dpp_sum(y), s2 = dpp_sum(y*y);
    float m = s*(1.f/64.f), var = fmaxf(s2*(1.f/64.f) - m*m, 0.f);
    float h1 = (y - m)*rsqrtf(var + 1e-5f)*g1[tid] + be1[tid];
    float z = h1 + cross[irow*64 + tid];
    float sz = dpp_sum(z), sz2 = dpp_sum(z*z);
    float mz = sz*(1.f/64.f), vz = fmaxf(sz2*(1.f/64.f) - mz*mz, 0.f);
    h2s[tid] = (z - mz)*rsqrtf(vz + 1e-5f)*g2[tid] + be2[tid];
  }
  __syncthreads();
  {
    const u32* w1r = (const u32*)(w1_b + tid*64);
    float acc = c1[tid];
    #pragma unroll
    for (int w = 0; w < 32; ++w){ float2 p = bp2(w1r[w]); acc += p.x*h2s[2*w] + p.y*h2s[2*w+1]; }
    fs[tid] = fmaxf(acc, 0.f);
  }
  __syncthreads();
  if (tid < 64){
    const u32* w2r = (const u32*)(w2_b + tid*128);
    float acc = c2[tid];
    #pragma unroll
    for (int w = 0; w < 64; ++w){ float2 p = bp2(w2r[w]); acc += p.x*fs[2*w] + p.y*fs[2*w+1]; }
    float y = h2s[tid] + acc;
    float s = dpp_sum(y), s2 = dpp_sum(y*y);
    float m = s*(1.f/64.f), var = fmaxf(s2*(1.f/64.f) - m*m, 0.f);
    h3s[tid] = (y - m)*rsqrtf(var + 1e-5f)*g3[tid] + be3[tid];
  }
  __syncthreads();
  if (tid < DOUT_){
    const u32* rr = (const u32*)(wr_b + tid*64);
    float acc = br[tid];
    #pragma unroll
    for (int w = 0; w < 32; ++w){ float2 p = bp2(rr[w]); acc += p.x*h3s[2*w] + p.y*h3s[2*w+1]; }
    out[irow*DOUT_ + tid] = acc;
  }
}

extern "C" void kernel_launch(void* const* d_in, const int* in_sizes, int n_in,
                              void* d_out, int out_size, void* d_ws, size_t ws_size,
                              hipStream_t stream){
  const float* audio=(const float*)d_in[0];
  const float* Wa   =(const float*)d_in[1];
  const float* ba   =(const float*)d_in[2];
  const float* objW =(const float*)d_in[3];
  const float* Wq   =(const float*)d_in[4];
  const float* bq   =(const float*)d_in[5];
  const float* Wk   =(const float*)d_in[6];
  const float* bk   =(const float*)d_in[7];
  const float* Wv   =(const float*)d_in[8];
  const float* bv   =(const float*)d_in[9];
  const float* Wo   =(const float*)d_in[10];
  const float* bo   =(const float*)d_in[11];
  const float* Wv2  =(const float*)d_in[12];
  const float* bv2  =(const float*)d_in[13];
  const float* Wo2  =(const float*)d_in[14];
  const float* bo2  =(const float*)d_in[15];
  const float* g1   =(const float*)d_in[16];
  const float* be1  =(const float*)d_in[17];
  const float* g2   =(const float*)d_in[18];
  const float* be2  =(const float*)d_in[19];
  const float* g3   =(const float*)d_in[20];
  const float* be3  =(const float*)d_in[21];
  const float* W1   =(const float*)d_in[22];
  const float* c1   =(const float*)d_in[23];
  const float* W2   =(const float*)d_in[24];
  const float* c2   =(const float*)d_in[25];
  const float* Wr   =(const float*)d_in[26];
  const float* br   =(const float*)d_in[27];
  const float* Wm   =(const float*)d_in[28];
  const float* bm   =(const float*)d_in[29];

  float* ws    = (float*)d_ws;
  float* mem   = ws;            // 120*64
  float* cross = ws + 7680;     // 120*64
  float* xw    = ws + 15360;    // 120*64
  float* Kw    = ws + 23040;    // 120*64
  float* Vw    = ws + 30720;    // 120*64
  u16* bb   = (u16*)(ws + 38400);
  u16* wv_b = bb;               // 4096
  u16* wo_b = bb + 4096;        // 4096
  u16* w1_b = bb + 8192;        // 8192
  u16* w2_b = bb + 16384;       // 8192
  u16* wr_b = bb + 24576;       // 1984
  float* out = (float*)d_out;

  k_prep <<<dim3(32),  dim3(256), 0, stream>>>(Wv, Wo, W1, W2, Wr, wv_b, wo_b, w1_b, w2_b, wr_b);
  k_mem  <<<dim3(120), dim3(256), 0, stream>>>(audio, Wa, ba, mem);
  k_cross<<<dim3(120), dim3(64),  0, stream>>>(mem, Wv2, bv2, Wo2, bo2, cross);
  k_scan <<<dim3(1),   dim3(128), 0, stream>>>(objW, Wq, bq, Wk, bk, bv, bo,
                                               g1, be1, g2, be2, g3, be3,
                                               c1, c2, br, Wm, bm,
                                               cross, wv_b, wo_b, w1_b, w2_b, wr_b,
                                               xw, Kw, Vw);
  k_final<<<dim3(120), dim3(128), 0, stream>>>(Wq, bq, bo, g1, be1, g2, be2, g3, be3,
                                               c1, c2, br, wo_b, w1_b, w2_b, wr_b,
                                               cross, xw, Kw, Vw, out);
}

// Round 5
// 440.554 us; speedup vs baseline: 2.4493x; 2.0009x over previous
//
#include <hip/hip_runtime.h>

typedef unsigned short u16;
typedef unsigned int   u32;
typedef _Float16 f16;
typedef f16 h2 __attribute__((ext_vector_type(2)));
typedef f16 h4 __attribute__((ext_vector_type(4)));
typedef f16 h8 __attribute__((ext_vector_type(8)));

#define T_    120
#define D_    64
#define DFF_  128
#define DOUT_ 31
#define KROW_ 68    // f16 per K-cache row (34 words -> 2-way bank alias on b64 reads: free)
#define VROW_ 132   // f16 per V^T-cache row (66 words -> 2-way: free)

#if defined(__has_builtin)
#if __has_builtin(__builtin_amdgcn_fdot2)
#define DOT2(a,b,c) __builtin_amdgcn_fdot2((a),(b),(c),false)
#endif
#endif
#ifndef DOT2
#define DOT2(a,b,c) ((float)(a).x*(float)(b).x + ((float)(a).y*(float)(b).y + (c)))
#endif
#define SHV(x,i,j) __builtin_shufflevector((x),(x),(i),(j))

__device__ __forceinline__ h2 pk(float a, float b){
#if defined(__has_builtin) && __has_builtin(__builtin_amdgcn_cvt_pkrtz)
  return __builtin_bit_cast(h2, __builtin_amdgcn_cvt_pkrtz(a, b));
#else
  h2 r; r.x = (f16)a; r.y = (f16)b; return r;
#endif
}

// ---------- bf16 helpers (k_prep / k_final use bf16 weight buffers) ----------
__device__ __forceinline__ float b2f(u16 u){ return __uint_as_float(((u32)u) << 16); }
__device__ __forceinline__ float2 bp2(u32 u){
  float2 r; r.x = __uint_as_float(u << 16); r.y = __uint_as_float(u & 0xffff0000u); return r;
}
__device__ __forceinline__ u16 f2bu(float f){
  u32 u = __float_as_uint(f);
  u32 r = u + 0x7fffu + ((u >> 16) & 1u);
  return (u16)(r >> 16);
}
#define WSYNC() do{ __asm__ __volatile__("" ::: "memory"); __builtin_amdgcn_wave_barrier(); }while(0)

__device__ __forceinline__ float dpp_sum(float x){
  int t;
  t = __builtin_amdgcn_update_dpp(0, __float_as_int(x), 0x111, 0xf, 0xf, true); x += __int_as_float(t);
  t = __builtin_amdgcn_update_dpp(0, __float_as_int(x), 0x112, 0xf, 0xf, true); x += __int_as_float(t);
  t = __builtin_amdgcn_update_dpp(0, __float_as_int(x), 0x114, 0xf, 0xf, true); x += __int_as_float(t);
  t = __builtin_amdgcn_update_dpp(0, __float_as_int(x), 0x118, 0xf, 0xf, true); x += __int_as_float(t);
  t = __builtin_amdgcn_update_dpp(0, __float_as_int(x), 0x142, 0xf, 0xf, true); x += __int_as_float(t);
  t = __builtin_amdgcn_update_dpp(0, __float_as_int(x), 0x143, 0xf, 0xf, true); x += __int_as_float(t);
  return __int_as_float(__builtin_amdgcn_readlane(__float_as_int(x), 63));
}
__device__ __forceinline__ float dpp_max_pos(float x){   // requires true max > 0
  int t;
  t = __builtin_amdgcn_update_dpp(0, __float_as_int(x), 0x111, 0xf, 0xf, true); x = fmaxf(x, __int_as_float(t));
  t = __builtin_amdgcn_update_dpp(0, __float_as_int(x), 0x112, 0xf, 0xf, true); x = fmaxf(x, __int_as_float(t));
  t = __builtin_amdgcn_update_dpp(0, __float_as_int(x), 0x114, 0xf, 0xf, true); x = fmaxf(x, __int_as_float(t));
  t = __builtin_amdgcn_update_dpp(0, __float_as_int(x), 0x118, 0xf, 0xf, true); x = fmaxf(x, __int_as_float(t));
  t = __builtin_amdgcn_update_dpp(0, __float_as_int(x), 0x142, 0xf, 0xf, true); x = fmaxf(x, __int_as_float(t));
  t = __builtin_amdgcn_update_dpp(0, __float_as_int(x), 0x143, 0xf, 0xf, true); x = fmaxf(x, __int_as_float(t));
  return __int_as_float(__builtin_amdgcn_readlane(__float_as_int(x), 63));
}
__device__ __forceinline__ float pe_val(int row, int i){
  const float coef = -0.28782313662425574f; // -ln(10000)/32
  int p = row % 10;
  float dv  = __expf((float)(i >> 1) * coef);
  float ang = (float)p * dv;
  return (i & 1) ? __cosf(ang) : __sinf(ang);
}
__device__ __forceinline__ void loadrow32(h2* dst, const float* row){
  #pragma unroll
  for (int r = 0; r < 16; ++r){
    float4 f = ((const float4*)row)[r];
    dst[2*r]   = pk(f.x, f.y);
    dst[2*r+1] = pk(f.z, f.w);
  }
}
__device__ __forceinline__ void loadrow64(h2* dst, const float* row){
  #pragma unroll
  for (int r = 0; r < 32; ++r){
    float4 f = ((const float4*)row)[r];
    dst[2*r]   = pk(f.x, f.y);
    dst[2*r+1] = pk(f.z, f.w);
  }
}

// ---------- kernel P: fp32 -> bf16 weight conversion (for k_final) ----------
__global__ __launch_bounds__(256) void k_prep(const float* __restrict__ Wv, const float* __restrict__ Wo,
                                              const float* __restrict__ W1, const float* __restrict__ W2,
                                              const float* __restrict__ Wr,
                                              u16* __restrict__ wvb, u16* __restrict__ wob,
                                              u16* __restrict__ w1b, u16* __restrict__ w2b,
                                              u16* __restrict__ wrb){
  int i0 = blockIdx.x*256 + threadIdx.x, stride = gridDim.x*256;
  for (int i = i0; i < 4096; i += stride){ wvb[i] = f2bu(Wv[i]); wob[i] = f2bu(Wo[i]); }
  for (int i = i0; i < 8192; i += stride){ w1b[i] = f2bu(W1[i]); w2b[i] = f2bu(W2[i]); }
  for (int i = i0; i < 1984; i += stride){ wrb[i] = f2bu(Wr[i]); }
}

// ---------- kernel A: mem = audio[0] @ W_audio^T + b_audio ----------
__global__ __launch_bounds__(256) void k_mem(const float* __restrict__ audio,
                                             const float* __restrict__ Wa,
                                             const float* __restrict__ ba,
                                             float* __restrict__ mem){
  __shared__ float ash[1024];
  const int t = blockIdx.x, tid = threadIdx.x;
  for (int i = tid; i < 1024; i += 256) ash[i] = audio[t*1024 + i];
  __syncthreads();
  const int w = tid >> 6, lane = tid & 63;
  for (int d = w*16; d < w*16 + 16; ++d){
    const float4* row = (const float4*)(Wa + d*1024);
    float acc = 0.f;
    #pragma unroll
    for (int m = 0; m < 4; ++m){
      float4 wp = row[lane + 64*m];
      int j = 4*(lane + 64*m);
      acc += wp.x*ash[j] + wp.y*ash[j+1] + wp.z*ash[j+2] + wp.w*ash[j+3];
    }
    acc = dpp_sum(acc);
    if (lane == 0) mem[t*64 + d] = acc + ba[d];
  }
}

// ---------- kernel B: cross ----------
__global__ __launch_bounds__(64) void k_cross(const float* __restrict__ mem,
                                              const float* __restrict__ Wv2, const float* __restrict__ bv2,
                                              const float* __restrict__ Wo2, const float* __restrict__ bo2,
                                              float* __restrict__ cross){
  __shared__ float msh[64], tsh[64];
  const int t = blockIdx.x, i = threadIdx.x;
  msh[i] = mem[t*64 + i];
  __syncthreads();
  const float4* r1 = (const float4*)(Wv2 + i*64);
  float a = bv2[i];
  #pragma unroll
  for (int j = 0; j < 16; ++j){ float4 w = r1[j]; a += w.x*msh[4*j] + w.y*msh[4*j+1] + w.z*msh[4*j+2] + w.w*msh[4*j+3]; }
  tsh[i] = a;
  __syncthreads();
  const float4* r2 = (const float4*)(Wo2 + i*64);
  float c = bo2[i];
  #pragma unroll
  for (int j = 0; j < 16; ++j){ float4 w = r2[j]; c += w.x*tsh[4*j] + w.y*tsh[4*j+1] + w.z*tsh[4*j+2] + w.w*tsh[4*j+3]; }
  cross[t*64 + i] = c;
}

// ---------- kernel C: sequential scan; weights in VGPRs (f16), handoffs f16 LDS ----------
__global__ __launch_bounds__(128, 1) void k_scan(
    const float* __restrict__ objW,
    const float* __restrict__ Wq, const float* __restrict__ bq,
    const float* __restrict__ Wk, const float* __restrict__ bk,
    const float* __restrict__ Wv, const float* __restrict__ bv,
    const float* __restrict__ Wo, const float* __restrict__ bo,
    const float* __restrict__ g1, const float* __restrict__ be1,
    const float* __restrict__ g2, const float* __restrict__ be2,
    const float* __restrict__ g3, const float* __restrict__ be3,
    const float* __restrict__ W1, const float* __restrict__ c1,
    const float* __restrict__ W2, const float* __restrict__ c2,
    const float* __restrict__ Wr, const float* __restrict__ br,
    const float* __restrict__ Wm, const float* __restrict__ bm,
    const float* __restrict__ cross,
    float* __restrict__ xw, float* __restrict__ Kw, float* __restrict__ Vw)
{
  __shared__ __align__(16) f16 KcS[128*KROW_];  // 17.0 KB
  __shared__ __align__(16) f16 VcS[D_*VROW_];   // 16.5 KB
  __shared__ __align__(16) f16 sch[256];
  __shared__ __align__(16) f16 xh[64], qh[64], ath[64], h2h[64], h3h[64], rsh[32];
  __shared__ __align__(16) f16 fsh[128];
  __shared__ float at_p[64];
  __shared__ float pe_tab[640];

  const int tid = threadIdx.x;
  const int i = tid & 63;
  const bool w0 = tid < 64;

  // ---- register-resident weights (f16 pairs). WA/WB aliased per wave. ----
  h2 WA[32];   // wave0: Wq row i   | wave1: Wk row i
  h2 WB[32];   // wave0: Wv row i   | wave1: W1 row 64+i
  h2 WOr[32], W1r[32], WRr[32], WMr[16];
  h2 W2r[64];
  float biasA=0.f, biasB=0.f, bo_r=0.f, c1r=0.f, c2_r=0.f, br_r=0.f, bmst=0.f, cls_r=0.f;
  float g1r=0.f,b1r=0.f,g2r=0.f,b2r=0.f,g3r=0.f,b3r=0.f, xr=0.f;

  if (w0){
    loadrow32(WA,  Wq + i*64);
    loadrow32(WB,  Wv + i*64);
    loadrow32(WOr, Wo + i*64);
    loadrow32(W1r, W1 + i*64);
    loadrow64(W2r, W2 + i*128);
    loadrow32(WRr, Wr + (i < 31 ? i : 30)*64);
    { const float* row = Wm + i*31;
      #pragma unroll
      for (int r = 0; r < 15; ++r) WMr[r] = pk(row[2*r], row[2*r+1]);
      WMr[15] = pk(row[30], 0.f); }
    biasA = bq[i]; biasB = bv[i]; bo_r = bo[i]; c1r = c1[i]; c2_r = c2[i];
    br_r = (i < 31) ? br[i] : 0.f;
    float st = objW[i*5];
    bmst = bm[i] + st;
    cls_r = cross[119*64 + i];
    g1r=g1[i]; b1r=be1[i]; g2r=g2[i]; b2r=be2[i]; g3r=g3[i]; b3r=be3[i];
    xr = st + pe_val(0, i);
    xh[i] = (f16)xr;
    xw[i] = xr;
  } else {
    loadrow32(WA, Wk + i*64);
    loadrow32(WB, W1 + (64+i)*64);
    biasA = bk[i]; c1r = c1[64+i];
  }
  // zero caches (pads must multiply as 0, not NaN-garbage)
  { u32* kcw = (u32*)KcS; for (int idx = tid; idx < 128*KROW_/2; idx += 128) kcw[idx] = 0; }
  { u32* vcw = (u32*)VcS; for (int idx = tid; idx < D_*VROW_/2;  idx += 128) vcw[idx] = 0; }
  for (int idx = tid; idx < 640; idx += 128) pe_tab[idx] = pe_val(idx >> 6, idx & 63);
  if (tid < 32) rsh[tid] = (f16)0.f;
  __syncthreads();

  int pp = 1;  // (t+1) % 10
  for (int t = 0; t < T_-1; ++t){
    float atp0 = 0.f;
    // ---- P1: q/v (wave0), k (wave1) from xh ----
    {
      const h8* xv = (const h8*)xh;
      float a0=biasA, a1=0.f, a2=0.f, a3=0.f;
      #pragma unroll
      for (int r = 0; r < 8; ++r){
        h8 x = xv[r];
        a0 = DOT2(WA[4*r+0], SHV(x,0,1), a0);
        a1 = DOT2(WA[4*r+1], SHV(x,2,3), a1);
        a2 = DOT2(WA[4*r+2], SHV(x,4,5), a2);
        a3 = DOT2(WA[4*r+3], SHV(x,6,7), a3);
      }
      float accA = (a0+a1)+(a2+a3);
      if (w0){
        float b0=biasB, b1=0.f, b2=0.f, b3=0.f;
        #pragma unroll
        for (int r = 0; r < 8; ++r){
          h8 x = xv[r];
          b0 = DOT2(WB[4*r+0], SHV(x,0,1), b0);
          b1 = DOT2(WB[4*r+1], SHV(x,2,3), b1);
          b2 = DOT2(WB[4*r+2], SHV(x,4,5), b2);
          b3 = DOT2(WB[4*r+3], SHV(x,6,7), b3);
        }
        float accB = (b0+b1)+(b2+b3);
        qh[i] = (f16)accA;
        VcS[i*VROW_ + t] = (f16)accB;
        Vw[t*64 + i] = accB;
      } else {
        KcS[t*KROW_ + i] = (f16)accA;
        Kw[t*64 + i] = accA;
      }
    }
    __syncthreads();
    // ---- P2+P3: wave h = head h; scores for rows j, j+64; softmax via DPP ----
    {
      const int h = tid >> 6, j = i;
      const h8* qv = (const h8*)(qh + h*32);
      const h4* k0 = (const h4*)(KcS + j*KROW_ + h*32);
      const h4* k1 = (const h4*)(KcS + (j+64)*KROW_ + h*32);
      float d0a=0.f,d0b=0.f,d1a=0.f,d1b=0.f;
      #pragma unroll
      for (int r = 0; r < 4; ++r){
        h8 q = qv[r];
        h4 ka = k0[2*r], kb = k0[2*r+1], kc = k1[2*r], kd = k1[2*r+1];
        d0a = DOT2(SHV(ka,0,1), SHV(q,0,1), d0a);
        d0b = DOT2(SHV(ka,2,3), SHV(q,2,3), d0b);
        d0a = DOT2(SHV(kb,0,1), SHV(q,4,5), d0a);
        d0b = DOT2(SHV(kb,2,3), SHV(q,6,7), d0b);
        d1a = DOT2(SHV(kc,0,1), SHV(q,0,1), d1a);
        d1b = DOT2(SHV(kc,2,3), SHV(q,2,3), d1b);
        d1a = DOT2(SHV(kd,0,1), SHV(q,4,5), d1a);
        d1b = DOT2(SHV(kd,2,3), SHV(q,6,7), d1b);
      }
      float d0 = d0a + d0b, d1 = d1a + d1b;
      const float slope = h ? 0.00390625f : 0.0625f;
      int r0 = (t - j) / 10, r1 = (t - j - 64) / 10;
      float s0 = (j      <= t) ? d0*0.17677669529663687f - slope*(float)r0 : -1e30f;
      float s1 = (j + 64 <= t) ? d1*0.17677669529663687f - slope*(float)r1 : -1e30f;
      float m = dpp_max_pos(fmaxf(s0, s1) + 16384.f) - 16384.f;
      float e0 = (j      <= t) ? __expf(s0 - m) : 0.f;
      float e1 = (j + 64 <= t) ? __expf(s1 - m) : 0.f;
      float inv = 1.f / dpp_sum(e0 + e1);
      sch[h*128 + j]      = (f16)(e0*inv);
      sch[h*128 + j + 64] = (f16)(e1*inv);
    }
    __syncthreads();
    // ---- P4: attn out; wave0 = positions 0..63, wave1 = 64..119 (pad zero) ----
    {
      const int hd = i >> 5;
      const h8* av = (const h8*)(sch + hd*128) + (w0 ? 0 : 8);
      const h4* vv = (const h4*)(VcS + i*VROW_) + (w0 ? 0 : 16);
      float p0=0.f,p1=0.f,p2=0.f,p3=0.f;
      #pragma unroll
      for (int r = 0; r < 8; ++r){
        h8 a = av[r];
        h4 va = vv[2*r], vb = vv[2*r+1];
        p0 = DOT2(SHV(va,0,1), SHV(a,0,1), p0);
        p1 = DOT2(SHV(va,2,3), SHV(a,2,3), p1);
        p2 = DOT2(SHV(vb,0,1), SHV(a,4,5), p2);
        p3 = DOT2(SHV(vb,2,3), SHV(a,6,7), p3);
      }
      float p = (p0+p1)+(p2+p3);
      if (!w0) at_p[i] = p; else atp0 = p;
    }
    __syncthreads();
    // ---- P5 (wave0): at combine; sa = at@Wo^T+bo; LN1; +cross_last; LN2 ----
    if (w0){
      float atv = atp0 + at_p[i];
      ath[i] = (f16)atv;
      WSYNC();
      const h8* av = (const h8*)ath;
      float a0=bo_r, a1=0.f, a2=0.f, a3=0.f;
      #pragma unroll
      for (int r = 0; r < 8; ++r){
        h8 x = av[r];
        a0 = DOT2(WOr[4*r+0], SHV(x,0,1), a0);
        a1 = DOT2(WOr[4*r+1], SHV(x,2,3), a1);
        a2 = DOT2(WOr[4*r+2], SHV(x,4,5), a2);
        a3 = DOT2(WOr[4*r+3], SHV(x,6,7), a3);
      }
      float y = xr + (a0+a1)+(a2+a3);
      float s = dpp_sum(y), s2 = dpp_sum(y*y);
      float m = s*(1.f/64.f), var = fmaxf(s2*(1.f/64.f) - m*m, 0.f);
      float h1 = (y - m)*rsqrtf(var + 1e-5f)*g1r + b1r;
      float z = h1 + cls_r;
      float sz = dpp_sum(z), sz2 = dpp_sum(z*z);
      float mz = sz*(1.f/64.f), vz = fmaxf(sz2*(1.f/64.f) - mz*mz, 0.f);
      float h2v = (z - mz)*rsqrtf(vz + 1e-5f)*g2r + b2r;
      h2h[i] = (f16)h2v;
      at_p[i] = h2v;                  // stash fp32 h2 for P7 residual (reuse at_p)
    }
    __syncthreads();
    // ---- P6: FFN1 (both waves; W1 row tid) ----
    {
      const h8* hv = (const h8*)h2h;
      float a0=c1r, a1=0.f, a2=0.f, a3=0.f;
      if (w0){
        #pragma unroll
        for (int r = 0; r < 8; ++r){
          h8 x = hv[r];
          a0 = DOT2(W1r[4*r+0], SHV(x,0,1), a0);
          a1 = DOT2(W1r[4*r+1], SHV(x,2,3), a1);
          a2 = DOT2(W1r[4*r+2], SHV(x,4,5), a2);
          a3 = DOT2(W1r[4*r+3], SHV(x,6,7), a3);
        }
      } else {
        #pragma unroll
        for (int r = 0; r < 8; ++r){
          h8 x = hv[r];
          a0 = DOT2(WB[4*r+0], SHV(x,0,1), a0);
          a1 = DOT2(WB[4*r+1], SHV(x,2,3), a1);
          a2 = DOT2(WB[4*r+2], SHV(x,4,5), a2);
          a3 = DOT2(WB[4*r+3], SHV(x,6,7), a3);
        }
      }
      fsh[tid] = (f16)fmaxf((a0+a1)+(a2+a3), 0.f);
    }
    __syncthreads();
    // ---- P7 (wave0): FFN2 + LN3 ; P8: Wr ; P9: Wm + pe ----
    if (w0){
      const h8* fv = (const h8*)fsh;
      float a0=c2_r, a1=0.f, a2=0.f, a3=0.f;
      #pragma unroll
      for (int r = 0; r < 16; ++r){
        h8 x = fv[r];
        a0 = DOT2(W2r[4*r+0], SHV(x,0,1), a0);
        a1 = DOT2(W2r[4*r+1], SHV(x,2,3), a1);
        a2 = DOT2(W2r[4*r+2], SHV(x,4,5), a2);
        a3 = DOT2(W2r[4*r+3], SHV(x,6,7), a3);
      }
      float y = at_p[i] + (a0+a1)+(a2+a3);   // h2 fp32 from stash
      float s = dpp_sum(y), s2 = dpp_sum(y*y);
      float m = s*(1.f/64.f), var = fmaxf(s2*(1.f/64.f) - m*m, 0.f);
      float h3v = (y - m)*rsqrtf(var + 1e-5f)*g3r + b3r;
      h3h[i] = (f16)h3v;
      WSYNC();
      // P8
      const h8* h3v8 = (const h8*)h3h;
      float r0=br_r, r1=0.f, r2=0.f, r3=0.f;
      #pragma unroll
      for (int r = 0; r < 8; ++r){
        h8 x = h3v8[r];
        r0 = DOT2(WRr[4*r+0], SHV(x,0,1), r0);
        r1 = DOT2(WRr[4*r+1], SHV(x,2,3), r1);
        r2 = DOT2(WRr[4*r+2], SHV(x,4,5), r2);
        r3 = DOT2(WRr[4*r+3], SHV(x,6,7), r3);
      }
      if (i < 31) rsh[i] = (f16)((r0+r1)+(r2+r3));
      WSYNC();
      // P9
      const h8* rv = (const h8*)rsh;
      float m0=bmst, m1=0.f, m2=0.f, m3=0.f;
      #pragma unroll
      for (int r = 0; r < 4; ++r){
        h8 x = rv[r];
        m0 = DOT2(WMr[4*r+0], SHV(x,0,1), m0);
        m1 = DOT2(WMr[4*r+1], SHV(x,2,3), m1);
        m2 = DOT2(WMr[4*r+2], SHV(x,4,5), m2);
        m3 = DOT2(WMr[4*r+3], SHV(x,6,7), m3);
      }
      float xn = (m0+m1)+(m2+m3) + pe_tab[pp*64 + i];
      xr = xn;
      xh[i] = (f16)xn;
      xw[(t+1)*64 + i] = xn;
    }
    __syncthreads();
    pp = (pp == 9) ? 0 : pp + 1;
  }
  // ---- epilogue: k,v for row 119 ----
  {
    const h8* xv = (const h8*)xh;
    if (w0){
      float b0=biasB, b1=0.f, b2=0.f, b3=0.f;
      #pragma unroll
      for (int r = 0; r < 8; ++r){
        h8 x = xv[r];
        b0 = DOT2(WB[4*r+0], SHV(x,0,1), b0);
        b1 = DOT2(WB[4*r+1], SHV(x,2,3), b1);
        b2 = DOT2(WB[4*r+2], SHV(x,4,5), b2);
        b3 = DOT2(WB[4*r+3], SHV(x,6,7), b3);
      }
      Vw[119*64 + i] = (b0+b1)+(b2+b3);
    } else {
      float a0=biasA, a1=0.f, a2=0.f, a3=0.f;
      #pragma unroll
      for (int r = 0; r < 8; ++r){
        h8 x = xv[r];
        a0 = DOT2(WA[4*r+0], SHV(x,0,1), a0);
        a1 = DOT2(WA[4*r+1], SHV(x,2,3), a1);
        a2 = DOT2(WA[4*r+2], SHV(x,4,5), a2);
        a3 = DOT2(WA[4*r+3], SHV(x,6,7), a3);
      }
      Kw[119*64 + i] = (a0+a1)+(a2+a3);
    }
  }
}

// ---------- kernel D: final full pass, one block per row ----------
__global__ __launch_bounds__(128) void k_final(
    const float* __restrict__ Wq, const float* __restrict__ bq, const float* __restrict__ bo,
    const float* __restrict__ g1, const float* __restrict__ be1,
    const float* __restrict__ g2, const float* __restrict__ be2,
    const float* __restrict__ g3, const float* __restrict__ be3,
    const float* __restrict__ c1, const float* __restrict__ c2, const float* __restrict__ br,
    const u16* __restrict__ wo_b, const u16* __restrict__ w1_b,
    const u16* __restrict__ w2_b, const u16* __restrict__ wr_b,
    const float* __restrict__ cross, const float* __restrict__ xw,
    const float* __restrict__ Kw, const float* __restrict__ Vw,
    float* __restrict__ out)
{
  __shared__ float xs[64], qs[64], at[64], h2s[64], h3s[64], fs[128], sc[256];
  const int irow = blockIdx.x, tid = threadIdx.x;
  if (tid < 64) xs[tid] = xw[irow*64 + tid];
  __syncthreads();
  if (tid < 64){
    const float4* wr_ = (const float4*)(Wq + tid*64);
    float acc = bq[tid];
    #pragma unroll
    for (int j = 0; j < 16; ++j){ float4 w = wr_[j]; acc += w.x*xs[4*j] + w.y*xs[4*j+1] + w.z*xs[4*j+2] + w.w*xs[4*j+3]; }
    qs[tid] = acc;
  }
  __syncthreads();
  {
    const int h = tid >> 6, j = tid & 63;
    const float* qh_ = qs + h*32;
    float d0 = 0.f, d1 = 0.f;
    const float4* k0 = (const float4*)(Kw + j*64 + h*32);
    #pragma unroll
    for (int w = 0; w < 8; ++w){ float4 p = k0[w]; d0 += p.x*qh_[4*w] + p.y*qh_[4*w+1] + p.z*qh_[4*w+2] + p.w*qh_[4*w+3]; }
    if (j < 56){
      const float4* k1 = (const float4*)(Kw + (j+64)*64 + h*32);
      #pragma unroll
      for (int w = 0; w < 8; ++w){ float4 p = k1[w]; d1 += p.x*qh_[4*w] + p.y*qh_[4*w+1] + p.z*qh_[4*w+2] + p.w*qh_[4*w+3]; }
    }
    const float slope = h ? 0.00390625f : 0.0625f;
    float s0 = (j      <= irow) ? d0*0.17677669529663687f - slope*(float)((irow-j)/10)    : -1e30f;
    float s1 = (j + 64 <= irow) ? d1*0.17677669529663687f - slope*(float)((irow-j-64)/10) : -1e30f;
    float m = dpp_max_pos(fmaxf(s0, s1) + 16384.f) - 16384.f;
    float e0 = (j      <= irow) ? __expf(s0 - m) : 0.f;
    float e1 = (j + 64 <= irow) ? __expf(s1 - m) : 0.f;
    float inv = 1.f / dpp_sum(e0 + e1);
    sc[h*128 + j]      = e0*inv;
    sc[h*128 + j + 64] = e1*inv;
  }
  __syncthreads();
  if (tid < 64){
    const float* a = sc + (tid >> 5)*128;
    float a0=0.f,a1=0.f,a2=0.f,a3=0.f;
    #pragma unroll
    for (int jj = 0; jj < 30; ++jj){
      a0 += a[4*jj]   * Vw[(4*jj)*64   + tid];
      a1 += a[4*jj+1] * Vw[(4*jj+1)*64 + tid];
      a2 += a[4*jj+2] * Vw[(4*jj+2)*64 + tid];
      a3 += a[4*jj+3] * Vw[(4*jj+3)*64 + tid];
    }
    at[tid] = (a0+a1)+(a2+a3);
  }
  __syncthreads();
  if (tid < 64){
    const u32* orow = (const u32*)(wo_b + tid*64);
    float acc = bo[tid];
    #pragma unroll
    for (int w = 0; w < 32; ++w){ float2 p = bp2(orow[w]); acc += p.x*at[2*w] + p.y*at[2*w+1]; }
    float y = xs[tid] + acc;
    float s = dpp_sum(y), s2 = dpp_sum(y*y);
    float m = s*(1.f/64.f), var = fmaxf(s2*(1.f/64.f) - m*m, 0.f);
    float h1 = (y - m)*rsqrtf(var + 1e-5f)*g1[tid] + be1[tid];
    float z = h1 + cross[irow*64 + tid];
    float sz = dpp_sum(z), sz2 = dpp_sum(z*z);
    float mz = sz*(1.f/64.f), vz = fmaxf(sz2*(1.f/64.f) - mz*mz, 0.f);
    h2s[tid] = (z - mz)*rsqrtf(vz + 1e-5f)*g2[tid] + be2[tid];
  }
  __syncthreads();
  {
    const u32* w1r = (const u32*)(w1_b + tid*64);
    float acc = c1[tid];
    #pragma unroll
    for (int w = 0; w < 32; ++w){ float2 p = bp2(w1r[w]); acc += p.x*h2s[2*w] + p.y*h2s[2*w+1]; }
    fs[tid] = fmaxf(acc, 0.f);
  }
  __syncthreads();
  if (tid < 64){
    const u32* w2r = (const u32*)(w2_b + tid*128);
    float acc = c2[tid];
    #pragma unroll
    for (int w = 0; w < 64; ++w){ float2 p = bp2(w2r[w]); acc += p.x*fs[2*w] + p.y*fs[2*w+1]; }
    float y = h2s[tid] + acc;
    float s = dpp_sum(y), s2 = dpp_sum(y*y);
    float m = s*(1.f/64.f), var = fmaxf(s2*(1.f/64.f) - m*m, 0.f);
    h3s[tid] = (y - m)*rsqrtf(var + 1e-5f)*g3[tid] + be3[tid];
  }
  __syncthreads();
  if (tid < DOUT_){
    const u32* rr = (const u32*)(wr_b + tid*64);
    float acc = br[tid];
    #pragma unroll
    for (int w = 0; w < 32; ++w){ float2 p = bp2(rr[w]); acc += p.x*h3s[2*w] + p.y*h3s[2*w+1]; }
    out[irow*DOUT_ + tid] = acc;
  }
}

extern "C" void kernel_launch(void* const* d_in, const int* in_sizes, int n_in,
                              void* d_out, int out_size, void* d_ws, size_t ws_size,
                              hipStream_t stream){
  const float* audio=(const float*)d_in[0];
  const float* Wa   =(const float*)d_in[1];
  const float* ba   =(const float*)d_in[2];
  const float* objW =(const float*)d_in[3];
  const float* Wq   =(const float*)d_in[4];
  const float* bq   =(const float*)d_in[5];
  const float* Wk   =(const float*)d_in[6];
  const float* bk   =(const float*)d_in[7];
  const float* Wv   =(const float*)d_in[8];
  const float* bv   =(const float*)d_in[9];
  const float* Wo   =(const float*)d_in[10];
  const float* bo   =(const float*)d_in[11];
  const float* Wv2  =(const float*)d_in[12];
  const float* bv2  =(const float*)d_in[13];
  const float* Wo2  =(const float*)d_in[14];
  const float* bo2  =(const float*)d_in[15];
  const float* g1   =(const float*)d_in[16];
  const float* be1  =(const float*)d_in[17];
  const float* g2   =(const float*)d_in[18];
  const float* be2  =(const float*)d_in[19];
  const float* g3   =(const float*)d_in[20];
  const float* be3  =(const float*)d_in[21];
  const float* W1   =(const float*)d_in[22];
  const float* c1   =(const float*)d_in[23];
  const float* W2   =(const float*)d_in[24];
  const float* c2   =(const float*)d_in[25];
  const float* Wr   =(const float*)d_in[26];
  const float* br   =(const float*)d_in[27];
  const float* Wm   =(const float*)d_in[28];
  const float* bm   =(const float*)d_in[29];

  float* ws    = (float*)d_ws;
  float* mem   = ws;            // 120*64
  float* cross = ws + 7680;     // 120*64
  float* xw    = ws + 15360;    // 120*64
  float* Kw    = ws + 23040;    // 120*64
  float* Vw    = ws + 30720;    // 120*64
  u16* bb   = (u16*)(ws + 38400);
  u16* wv_b = bb;               // 4096
  u16* wo_b = bb + 4096;        // 4096
  u16* w1_b = bb + 8192;        // 8192
  u16* w2_b = bb + 16384;       // 8192
  u16* wr_b = bb + 24576;       // 1984
  float* out = (float*)d_out;

  k_prep <<<dim3(32),  dim3(256), 0, stream>>>(Wv, Wo, W1, W2, Wr, wv_b, wo_b, w1_b, w2_b, wr_b);
  k_mem  <<<dim3(120), dim3(256), 0, stream>>>(audio, Wa, ba, mem);
  k_cross<<<dim3(120), dim3(64),  0, stream>>>(mem, Wv2, bv2, Wo2, bo2, cross);
  k_scan <<<dim3(1),   dim3(128), 0, stream>>>(objW, Wq, bq, Wk, bk, Wv, bv, Wo, bo,
                                               g1, be1, g2, be2, g3, be3,
                                               W1, c1, W2, c2, Wr, br, Wm, bm,
                                               cross, xw, Kw, Vw);
  k_final<<<dim3(120), dim3(128), 0, stream>>>(Wq, bq, bo, g1, be1, g2, be2, g3, be3,
                                               c1, c2, br, wo_b, w1_b, w2_b, wr_b,
                                               cross, xw, Kw, Vw, out);
}